// Round 16
// baseline (125.597 us; speedup 1.0000x reference)
//
#include <hip/hip_runtime.h>

// CfC cell, fp16-MFMA implementation.
//   h   = 1.7159*tanh(0.666*(concat(input,hx) @ Wb^T + bb))   [B,1024]
//   ff1 = tanh(h@W1^T+b1), ff2 = tanh(h@W2^T+b2)
//   t   = sigmoid((h@Wa^T+ba)*ts + (h@Wt^T+bt))
//   out = ff1 + t*(ff2-ff1)                                   [B,512]
// Round 16: faithful m201-style 8-phase counted-vmcnt schedule.
// 256^2 tile, BK=64, 8 waves as 2M x 4N (wave = 128 rows x 64 cols).
// Per K-tile: 4 phases x 16 MFMA (quadrants), reads phase-local.
// 8-phase iter = 2 K-tiles. Stage slots: ph1,2 = A(2i+1); ph3,4 = B(2i+2);
// ph5,6 = A(2i+2); ph7,8 = B(2i+3). Hand-verified: every staged region's
// prior reads ended >=1 phase before the stage issue (A-halves free after
// ph1/ph5, B-halves after ph2/ph6); vmcnt(4) at ph4/ph8 covers exactly the
// tiles needed next with 2-6 phase issue->wait lead; NO vmcnt(0) in the
// steady loop (the invariant every earlier failed variant lacked).
// Prologue: A(0),B(0),B(1) staged (12 calls), vmcnt(4). Last iter: no
// stages, ph4 vmcnt(0), ph8 falls to epilogue. fast_tanh epilogues,
// r3-verified swizzle, r12 XCD maps, head-interleaved Wh (n-frag == head).

typedef _Float16 f16;
typedef _Float16 f16x8 __attribute__((ext_vector_type(8)));
typedef _Float16 f16x4 __attribute__((ext_vector_type(4)));
typedef float f32x4 __attribute__((ext_vector_type(4)));

static constexpr int B_ = 16384, IN_ = 256, HID_ = 512, UNITS_ = 1024, CAT_ = 768;

__device__ __forceinline__ void gload_lds16(const void* g, void* l) {
  __builtin_amdgcn_global_load_lds(
      (const __attribute__((address_space(1))) void*)g,
      (__attribute__((address_space(3))) void*)l, 16, 0, 0);
}

__device__ __forceinline__ float fast_tanh(float x) {
  const float e = __expf(2.0f * x);
  return 1.0f - 2.0f / (e + 1.0f);
}

#define MFMA16(a, b, c) __builtin_amdgcn_mfma_f32_16x16x32_f16((a), (b), (c), 0, 0, 0)
#define BARRIER() do { asm volatile("" ::: "memory"); __builtin_amdgcn_s_barrier(); asm volatile("" ::: "memory"); } while (0)
#define VMCNT(n) asm volatile("s_waitcnt vmcnt(" #n ")" ::: "memory")

// ---- prep: build x=concat(input,hx) as f16; cast Wb; head-interleave Wh --
// [0,12288) build_x | [12288,13056) Wb | [13056,15104) Wh   (all exact)

__global__ void prep_kernel(const float* __restrict__ inp,
                            const float* __restrict__ hx,
                            const float* __restrict__ Wb,
                            const float* __restrict__ W1,
                            const float* __restrict__ W2,
                            const float* __restrict__ Wa,
                            const float* __restrict__ Wt,
                            f16* __restrict__ x,
                            f16* __restrict__ dWb, f16* __restrict__ dWh) {
  const int blk = blockIdx.x;
  if (blk < 12288) {
    const int gid = blk * 256 + threadIdx.x;       // < 16384*192 exact
    const int per_row = CAT_ / 4;                  // 192
    int b = gid / per_row, j = gid - b * per_row;
    float4 v;
    if (j < IN_ / 4) v = ((const float4*)(inp + (size_t)b * IN_))[j];
    else             v = ((const float4*)(hx  + (size_t)b * HID_))[j - IN_ / 4];
    f16x4 o = {(f16)v.x, (f16)v.y, (f16)v.z, (f16)v.w};
    *((f16x4*)(x + (size_t)b * CAT_ + j * 4)) = o;
  } else if (blk < 13056) {
    const int i = (blk - 12288) * 256 + threadIdx.x;  // < 196608 exact
    float4 v = ((const float4*)Wb)[i];
    f16x4 o = {(f16)v.x, (f16)v.y, (f16)v.z, (f16)v.w};
    ((f16x4*)dWb)[i] = o;
  } else {
    const int i = (blk - 13056) * 256 + threadIdx.x;  // < 524288 exact
    const int np = i >> 8;                   // n' row in [0,2048)
    const int k4 = i & 255;
    const int h = (np >> 4) & 3;
    const int c = ((np >> 6) << 4) | (np & 15);
    const float* srcs[4] = {W1, W2, Wa, Wt};
    float4 v = *((const float4*)(srcs[h] + (size_t)c * UNITS_ + k4 * 4));
    f16x4 o = {(f16)v.x, (f16)v.y, (f16)v.z, (f16)v.w};
    *((f16x4*)(dWh + (size_t)np * UNITS_ + k4 * 4)) = o;
  }
}

// ---- shared geometry ----------------------------------------------------
// 512 thr / 8 waves: wr = wid>>2 (A-half, 128 rows), wc = wid&3 (64-col set).
// LDS: As[2][2][128*64], Bs[2][2][128*64] = 128 KB. Staging call = 8 KB
// (64 rows x 128B): thread t -> row (t>>3) [+64 for q=1], phys chunk t&7,
// source chunk (t&7)^((t>>3)&7) [r3/r12-verified]. Read: row m*16+fr ->
// row&7 == fr&7; phys chunk kk*4+klo XOR (fr&7) -> cs0/cs1 [verified].

// ---- GEMM1: h = lecun_tanh(X @ Wb^T + bb) ------------------------------
// M=16384 N=1024 K=768 (NT=12, 6 iters). Grid 256; br=(bid>>5)*8+(bid&7).

__global__ __launch_bounds__(512, 2) void gemm1_kernel(
    const f16* __restrict__ X, const f16* __restrict__ Wb,
    const float* __restrict__ bb, f16* __restrict__ H) {
  constexpr int K = CAT_, BK = 64, NT = K / BK, ITERS = NT / 2;  // 12, 6
  __shared__ f16 As[2][2][8192];
  __shared__ f16 Bs[2][2][8192];
  const int t = threadIdx.x;
  const int lane = t & 63, wid = t >> 6;
  const int wr = wid >> 2;          // 0..1 : A-half / 128-row band
  const int wc = wid & 3;           // 0..3 : 64-col set
  const int bc = (blockIdx.x >> 3) & 3;
  const int br = (blockIdx.x >> 5) * 8 + (blockIdx.x & 7);
  const int arow0 = br * 256;
  const int bn0 = bc * 256;

  f32x4 acc[8][4] = {};  // [m 0..7][n 0..3]

  const int tr = t >> 3;
  const int sch = ((t & 7) ^ (tr & 7)) * 8;
  const f16* aSrc = X + (size_t)(arow0 + tr) * K + sch;
  const f16* bSrc = Wb + (size_t)(bn0 + tr) * K + sch;

  const int fr = lane & 15, klo = lane >> 4;
  const int cs0 = (klo ^ (fr & 7)) * 8;
  const int cs1 = ((klo + 4) ^ (fr & 7)) * 8;
  const int cb = (wc & 1) * 64;     // col base within B-half
  const int bh = wc >> 1;           // B-half index

#define SA(d, h, q, kt) gload_lds16(aSrc + (size_t)((h) * 128 + (q) * 64) * K + (kt) * BK, &As[d][h][(q) * 4096 + t * 8])
#define SB(d, h, q, kt) gload_lds16(bSrc + (size_t)((h) * 128 + (q) * 64) * K + (kt) * BK, &Bs[d][h][(q) * 4096 + t * 8])

  // prologue: A(0), B(0), B(1); leave B(1)'s 4 calls in flight
  SA(0, 0, 0, 0); SA(0, 0, 1, 0); SA(0, 1, 0, 0); SA(0, 1, 1, 0);
  SB(0, 0, 0, 0); SB(0, 0, 1, 0); SB(0, 1, 0, 0); SB(0, 1, 1, 0);
  SB(1, 0, 0, 1); SB(1, 0, 1, 1); SB(1, 1, 0, 1); SB(1, 1, 1, 1);
  VMCNT(4);
  BARRIER();

  f16x8 a[4][2], b0[2][2], b1[2][2];

  for (int it = 0; it < ITERS; ++it) {
    const bool last = (it == ITERS - 1);
    const int tp1 = 2 * it + 1, tp2 = 2 * it + 2, tp3 = 2 * it + 3;
    const bool sb3 = (tp3 < NT);

#pragma unroll
    for (int half = 0; half < 2; ++half) {  // half 0: tile 2i (buf0), 1: tile 2i+1 (buf1)
      // ---- phase A (ph1/ph5): reads a m0-3 + b n0-1; stage
#pragma unroll
      for (int m = 0; m < 4; ++m) {
        const int r = (m * 16 + fr) * 64;
        a[m][0] = *((const f16x8*)(&As[half][wr][r + cs0]));
        a[m][1] = *((const f16x8*)(&As[half][wr][r + cs1]));
      }
#pragma unroll
      for (int n = 0; n < 2; ++n) {
        const int r = (cb + n * 16 + fr) * 64;
        b0[n][0] = *((const f16x8*)(&Bs[half][bh][r + cs0]));
        b0[n][1] = *((const f16x8*)(&Bs[half][bh][r + cs1]));
      }
      if (half == 0) { SA(1, 0, 0, tp1); SA(1, 0, 1, tp1); }          // A0(2i+1)
      else if (!last) { SA(0, 0, 0, tp2); SA(0, 0, 1, tp2); }         // A0(2i+2)
      BARRIER();
      __builtin_amdgcn_s_setprio(1);
#pragma unroll
      for (int m = 0; m < 4; ++m)
#pragma unroll
        for (int n = 0; n < 2; ++n)
#pragma unroll
          for (int kk = 0; kk < 2; ++kk)
            acc[m][n] = MFMA16(a[m][kk], b0[n][kk], acc[m][n]);
      __builtin_amdgcn_s_setprio(0);
      BARRIER();

      // ---- phase B (ph2/ph6): reads b n2-3; stage
#pragma unroll
      for (int n = 0; n < 2; ++n) {
        const int r = (cb + 32 + n * 16 + fr) * 64;
        b1[n][0] = *((const f16x8*)(&Bs[half][bh][r + cs0]));
        b1[n][1] = *((const f16x8*)(&Bs[half][bh][r + cs1]));
      }
      if (half == 0) { SA(1, 1, 0, tp1); SA(1, 1, 1, tp1); }          // A1(2i+1)
      else if (!last) { SA(0, 1, 0, tp2); SA(0, 1, 1, tp2); }         // A1(2i+2)
      BARRIER();
      __builtin_amdgcn_s_setprio(1);
#pragma unroll
      for (int m = 0; m < 4; ++m)
#pragma unroll
        for (int n = 0; n < 2; ++n)
#pragma unroll
          for (int kk = 0; kk < 2; ++kk)
            acc[m][2 + n] = MFMA16(a[m][kk], b1[n][kk], acc[m][2 + n]);
      __builtin_amdgcn_s_setprio(0);
      BARRIER();

      // ---- phase C (ph3/ph7): reads a m4-7; stage
#pragma unroll
      for (int m = 0; m < 4; ++m) {
        const int r = (64 + m * 16 + fr) * 64;
        a[m][0] = *((const f16x8*)(&As[half][wr][r + cs0]));
        a[m][1] = *((const f16x8*)(&As[half][wr][r + cs1]));
      }
      if (half == 0) { if (!last) { SB(0, 0, 0, tp2); SB(0, 0, 1, tp2); } }  // B0(2i+2)
      else if (sb3) { SB(1, 0, 0, tp3); SB(1, 0, 1, tp3); }                 // B0(2i+3)
      BARRIER();
      __builtin_amdgcn_s_setprio(1);
#pragma unroll
      for (int m = 0; m < 4; ++m)
#pragma unroll
        for (int n = 0; n < 2; ++n)
#pragma unroll
          for (int kk = 0; kk < 2; ++kk)
            acc[4 + m][2 + n] = MFMA16(a[m][kk], b1[n][kk], acc[4 + m][2 + n]);
      __builtin_amdgcn_s_setprio(0);
      BARRIER();

      // ---- phase D (ph4/ph8): no reads; stage; counted wait
      if (half == 0) { if (!last) { SB(0, 1, 0, tp2); SB(0, 1, 1, tp2); } }  // B1(2i+2)
      else if (sb3) { SB(1, 1, 0, tp3); SB(1, 1, 1, tp3); }                 // B1(2i+3)
      BARRIER();
      __builtin_amdgcn_s_setprio(1);
#pragma unroll
      for (int m = 0; m < 4; ++m)
#pragma unroll
        for (int n = 0; n < 2; ++n)
#pragma unroll
          for (int kk = 0; kk < 2; ++kk)
            acc[4 + m][n] = MFMA16(a[m][kk], b0[n][kk], acc[4 + m][n]);
      __builtin_amdgcn_s_setprio(0);
      if (half == 0) {
        if (!last) VMCNT(4); else VMCNT(0);
        BARRIER();
      } else if (!last) {
        VMCNT(4);
        BARRIER();
      }
    }
  }
#undef SA
#undef SB

  // epilogue: wave = rows wr*128 + m*16 + klo*4 + i, cols bn0 + wc*64 + n*16 + fr
#pragma unroll
  for (int n = 0; n < 4; ++n) {
    const int colg = bn0 + wc * 64 + n * 16 + fr;
    const float bias = bb[colg];
#pragma unroll
    for (int m = 0; m < 8; ++m)
#pragma unroll
      for (int i = 0; i < 4; ++i) {
        const int rowg = arow0 + wr * 128 + m * 16 + klo * 4 + i;
        float v = acc[m][n][i] + bias;
        v = 1.7159f * fast_tanh(0.666f * v);
        H[(size_t)rowg * UNITS_ + colg] = (f16)v;
      }
  }
}

// ---- GEMM2: four heads fused, same 8-phase template ---------------------
// M=16384 N'=2048 K=1024 (NT=16, 8 iters). Grid 512; br=(bid>>6)*8+(bid&7).
// Wave's 4 n-frags == the 4 heads of ONE HID col-set: colg=(bc*4+wc)*16+fr.

__global__ __launch_bounds__(512, 2) void gemm2_kernel(
    const f16* __restrict__ Hm, const f16* __restrict__ Wp,
    const float* __restrict__ b1v, const float* __restrict__ b2v,
    const float* __restrict__ bav, const float* __restrict__ btv,
    const float* __restrict__ ts, float* __restrict__ out) {
  constexpr int K = UNITS_, BK = 64, NT = K / BK, ITERS = NT / 2;  // 16, 8
  __shared__ f16 As[2][2][8192];
  __shared__ f16 Bs[2][2][8192];
  const int t = threadIdx.x;
  const int lane = t & 63, wid = t >> 6;
  const int wr = wid >> 2;          // 0..1
  const int wc = wid & 3;           // 0..3
  const int bc = (blockIdx.x >> 3) & 7;
  const int br = (blockIdx.x >> 6) * 8 + (blockIdx.x & 7);
  const int arow0 = br * 256;
  const int bn0 = bc * 256;

  f32x4 acc[8][4] = {};  // [m 0..7][head 0..3]

  const int tr = t >> 3;
  const int sch = ((t & 7) ^ (tr & 7)) * 8;
  const f16* aSrc = Hm + (size_t)(arow0 + tr) * K + sch;
  const f16* bSrc = Wp + (size_t)(bn0 + tr) * K + sch;

  const int fr = lane & 15, klo = lane >> 4;
  const int cs0 = (klo ^ (fr & 7)) * 8;
  const int cs1 = ((klo + 4) ^ (fr & 7)) * 8;
  const int cb = (wc & 1) * 64;
  const int bh = wc >> 1;

#define SA(d, h, q, kt) gload_lds16(aSrc + (size_t)((h) * 128 + (q) * 64) * K + (kt) * BK, &As[d][h][(q) * 4096 + t * 8])
#define SB(d, h, q, kt) gload_lds16(bSrc + (size_t)((h) * 128 + (q) * 64) * K + (kt) * BK, &Bs[d][h][(q) * 4096 + t * 8])

  SA(0, 0, 0, 0); SA(0, 0, 1, 0); SA(0, 1, 0, 0); SA(0, 1, 1, 0);
  SB(0, 0, 0, 0); SB(0, 0, 1, 0); SB(0, 1, 0, 0); SB(0, 1, 1, 0);
  SB(1, 0, 0, 1); SB(1, 0, 1, 1); SB(1, 1, 0, 1); SB(1, 1, 1, 1);
  VMCNT(4);
  BARRIER();

  f16x8 a[4][2], b0[2][2], b1[2][2];

  for (int it = 0; it < ITERS; ++it) {
    const bool last = (it == ITERS - 1);
    const int tp1 = 2 * it + 1, tp2 = 2 * it + 2, tp3 = 2 * it + 3;
    const bool sb3 = (tp3 < NT);

#pragma unroll
    for (int half = 0; half < 2; ++half) {
      // ---- phase A
#pragma unroll
      for (int m = 0; m < 4; ++m) {
        const int r = (m * 16 + fr) * 64;
        a[m][0] = *((const f16x8*)(&As[half][wr][r + cs0]));
        a[m][1] = *((const f16x8*)(&As[half][wr][r + cs1]));
      }
#pragma unroll
      for (int n = 0; n < 2; ++n) {
        const int r = (cb + n * 16 + fr) * 64;
        b0[n][0] = *((const f16x8*)(&Bs[half][bh][r + cs0]));
        b0[n][1] = *((const f16x8*)(&Bs[half][bh][r + cs1]));
      }
      if (half == 0) { SA(1, 0, 0, tp1); SA(1, 0, 1, tp1); }
      else if (!last) { SA(0, 0, 0, tp2); SA(0, 0, 1, tp2); }
      BARRIER();
      __builtin_amdgcn_s_setprio(1);
#pragma unroll
      for (int m = 0; m < 4; ++m)
#pragma unroll
        for (int n = 0; n < 2; ++n)
#pragma unroll
          for (int kk = 0; kk < 2; ++kk)
            acc[m][n] = MFMA16(a[m][kk], b0[n][kk], acc[m][n]);
      __builtin_amdgcn_s_setprio(0);
      BARRIER();

      // ---- phase B
#pragma unroll
      for (int n = 0; n < 2; ++n) {
        const int r = (cb + 32 + n * 16 + fr) * 64;
        b1[n][0] = *((const f16x8*)(&Bs[half][bh][r + cs0]));
        b1[n][1] = *((const f16x8*)(&Bs[half][bh][r + cs1]));
      }
      if (half == 0) { SA(1, 1, 0, tp1); SA(1, 1, 1, tp1); }
      else if (!last) { SA(0, 1, 0, tp2); SA(0, 1, 1, tp2); }
      BARRIER();
      __builtin_amdgcn_s_setprio(1);
#pragma unroll
      for (int m = 0; m < 4; ++m)
#pragma unroll
        for (int n = 0; n < 2; ++n)
#pragma unroll
          for (int kk = 0; kk < 2; ++kk)
            acc[m][2 + n] = MFMA16(a[m][kk], b1[n][kk], acc[m][2 + n]);
      __builtin_amdgcn_s_setprio(0);
      BARRIER();

      // ---- phase C
#pragma unroll
      for (int m = 0; m < 4; ++m) {
        const int r = (64 + m * 16 + fr) * 64;
        a[m][0] = *((const f16x8*)(&As[half][wr][r + cs0]));
        a[m][1] = *((const f16x8*)(&As[half][wr][r + cs1]));
      }
      if (half == 0) { if (!last) { SB(0, 0, 0, tp2); SB(0, 0, 1, tp2); } }
      else if (sb3) { SB(1, 0, 0, tp3); SB(1, 0, 1, tp3); }
      BARRIER();
      __builtin_amdgcn_s_setprio(1);
#pragma unroll
      for (int m = 0; m < 4; ++m)
#pragma unroll
        for (int n = 0; n < 2; ++n)
#pragma unroll
          for (int kk = 0; kk < 2; ++kk)
            acc[4 + m][2 + n] = MFMA16(a[m][kk], b1[n][kk], acc[4 + m][2 + n]);
      __builtin_amdgcn_s_setprio(0);
      BARRIER();

      // ---- phase D
      if (half == 0) { if (!last) { SB(0, 1, 0, tp2); SB(0, 1, 1, tp2); } }
      else if (sb3) { SB(1, 1, 0, tp3); SB(1, 1, 1, tp3); }
      BARRIER();
      __builtin_amdgcn_s_setprio(1);
#pragma unroll
      for (int m = 0; m < 4; ++m)
#pragma unroll
        for (int n = 0; n < 2; ++n)
#pragma unroll
          for (int kk = 0; kk < 2; ++kk)
            acc[4 + m][n] = MFMA16(a[m][kk], b0[n][kk], acc[4 + m][n]);
      __builtin_amdgcn_s_setprio(0);
      if (half == 0) {
        if (!last) VMCNT(4); else VMCNT(0);
        BARRIER();
      } else if (!last) {
        VMCNT(4);
        BARRIER();
      }
    }
  }
#undef SA
#undef SB

  // epilogue: n-frag == head; one HID col per lane: colg = (bc*4+wc)*16+fr
  const int colg = (bc * 4 + wc) * 16 + fr;  // 0..511
  const float B1 = b1v[colg], B2 = b2v[colg], BA = bav[colg], BT = btv[colg];
#pragma unroll
  for (int m = 0; m < 8; ++m) {
#pragma unroll
    for (int i = 0; i < 4; ++i) {
      const int rowg = arow0 + wr * 128 + m * 16 + klo * 4 + i;
      const float ff1 = fast_tanh(acc[m][0][i] + B1);
      const float ff2 = fast_tanh(acc[m][1][i] + B2);
      const float ta = acc[m][2][i] + BA;
      const float tb = acc[m][3][i] + BT;
      const float z = ta * ts[rowg] + tb;
      const float ti = 1.0f / (1.0f + __expf(-z));
      out[(size_t)rowg * HID_ + colg] = ff1 + ti * (ff2 - ff1);
    }
  }
}

// ---- launch -------------------------------------------------------------

extern "C" void kernel_launch(void* const* d_in, const int* in_sizes, int n_in,
                              void* d_out, int out_size, void* d_ws, size_t ws_size,
                              hipStream_t stream) {
  const float* input = (const float*)d_in[0];
  const float* hx    = (const float*)d_in[1];
  const float* ts    = (const float*)d_in[2];
  const float* Wb    = (const float*)d_in[3];
  const float* bb    = (const float*)d_in[4];
  const float* W1    = (const float*)d_in[5];
  const float* b1    = (const float*)d_in[6];
  const float* W2    = (const float*)d_in[7];
  const float* b2    = (const float*)d_in[8];
  const float* Wa    = (const float*)d_in[9];
  const float* ba    = (const float*)d_in[10];
  const float* Wt    = (const float*)d_in[11];
  const float* bt    = (const float*)d_in[12];
  float* out = (float*)d_out;

  char* ws = (char*)d_ws;
  f16* x_f16  = (f16*)ws;  ws += (size_t)B_ * CAT_ * 2;
  f16* h_f16  = (f16*)ws;  ws += (size_t)B_ * UNITS_ * 2;
  f16* Wb_f16 = (f16*)ws;  ws += (size_t)UNITS_ * CAT_ * 2;
  f16* Wh_f16 = (f16*)ws;  ws += (size_t)4 * HID_ * UNITS_ * 2;

  prep_kernel<<<dim3(15104), 256, 0, stream>>>(input, hx, Wb, W1, W2, Wa, Wt,
                                               x_f16, Wb_f16, Wh_f16);
  gemm1_kernel<<<dim3(256), 512, 0, stream>>>(x_f16, Wb_f16, bb, h_f16);
  gemm2_kernel<<<dim3(512), 512, 0, stream>>>(h_f16, Wh_f16, b1, b2, ba, bt, ts, out);
}

// Round 17
// 122.391 us; speedup vs baseline: 1.0262x; 1.0262x over previous
//
#include <hip/hip_runtime.h>

// CfC cell, fp16-MFMA implementation.  (r17 == r12/r15 champion, restored)
//   h   = 1.7159*tanh(0.666*(concat(input,hx) @ Wb^T + bb))   [B,1024]
//   ff1 = tanh(h@W1^T+b1), ff2 = tanh(h@W2^T+b2)
//   t   = sigmoid((h@Wa^T+ba)*ts + (h@Wt^T+bt))
//   out = ff1 + t*(ff2-ff1)                                   [B,512]
// Champion config (122.6 us total; gemm2 80.3 us / 855 TF):
// 256^2 tile, BK=64, 8 waves (4Mx2N), 2x64KB LDS dbuf, single-barrier
// K-tile (one vmcnt(0)+s_barrier per tile), c1 gates on 12 ds_reads with
// b1/a1 read under c1's MFMA shadow, setprio around MFMA clusters,
// bijective XCD-aware grid maps, head-interleaved Wh (frag n == head,
// fully fused epilogue), fast_tanh epilogues, single prep kernel.
// Final ledger (gemm2 us): naive-dbuf 106 | 3-buf vmcnt 105 | 4-phase 100
// | deep-prefetch 103 | single-barrier 89 | +shadow-reads+fast_tanh 80.3
// | co-residency variants 88-95 | BK32-counted 93 | 8-phase-counted 85.3.
// MfmaUtil 37.5% == the documented plain-HIP 2-barrier-structure plateau.

typedef _Float16 f16;
typedef _Float16 f16x8 __attribute__((ext_vector_type(8)));
typedef _Float16 f16x4 __attribute__((ext_vector_type(4)));
typedef float f32x4 __attribute__((ext_vector_type(4)));

static constexpr int B_ = 16384, IN_ = 256, HID_ = 512, UNITS_ = 1024, CAT_ = 768;

__device__ __forceinline__ void gload_lds16(const void* g, void* l) {
  __builtin_amdgcn_global_load_lds(
      (const __attribute__((address_space(1))) void*)g,
      (__attribute__((address_space(3))) void*)l, 16, 0, 0);
}

__device__ __forceinline__ float fast_tanh(float x) {
  const float e = __expf(2.0f * x);
  return 1.0f - 2.0f / (e + 1.0f);
}

#define MFMA16(a, b, c) __builtin_amdgcn_mfma_f32_16x16x32_f16((a), (b), (c), 0, 0, 0)
#define BARRIER() do { asm volatile("" ::: "memory"); __builtin_amdgcn_s_barrier(); asm volatile("" ::: "memory"); } while (0)

// ---- prep: build x=concat(input,hx) as f16; cast Wb; head-interleave Wh --
// [0,12288) build_x | [12288,13056) Wb | [13056,15104) Wh   (all exact)

__global__ void prep_kernel(const float* __restrict__ inp,
                            const float* __restrict__ hx,
                            const float* __restrict__ Wb,
                            const float* __restrict__ W1,
                            const float* __restrict__ W2,
                            const float* __restrict__ Wa,
                            const float* __restrict__ Wt,
                            f16* __restrict__ x,
                            f16* __restrict__ dWb, f16* __restrict__ dWh) {
  const int blk = blockIdx.x;
  if (blk < 12288) {
    const int gid = blk * 256 + threadIdx.x;       // < 16384*192 exact
    const int per_row = CAT_ / 4;                  // 192
    int b = gid / per_row, j = gid - b * per_row;
    float4 v;
    if (j < IN_ / 4) v = ((const float4*)(inp + (size_t)b * IN_))[j];
    else             v = ((const float4*)(hx  + (size_t)b * HID_))[j - IN_ / 4];
    f16x4 o = {(f16)v.x, (f16)v.y, (f16)v.z, (f16)v.w};
    *((f16x4*)(x + (size_t)b * CAT_ + j * 4)) = o;
  } else if (blk < 13056) {
    const int i = (blk - 12288) * 256 + threadIdx.x;  // < 196608 exact
    float4 v = ((const float4*)Wb)[i];
    f16x4 o = {(f16)v.x, (f16)v.y, (f16)v.z, (f16)v.w};
    ((f16x4*)dWb)[i] = o;
  } else {
    const int i = (blk - 13056) * 256 + threadIdx.x;  // < 524288 exact
    const int np = i >> 8;                   // n' row in [0,2048)
    const int k4 = i & 255;
    const int h = (np >> 4) & 3;
    const int c = ((np >> 6) << 4) | (np & 15);
    const float* srcs[4] = {W1, W2, Wa, Wt};
    float4 v = *((const float4*)(srcs[h] + (size_t)c * UNITS_ + k4 * 4));
    f16x4 o = {(f16)v.x, (f16)v.y, (f16)v.z, (f16)v.w};
    *((f16x4*)(dWh + (size_t)np * UNITS_ + k4 * 4)) = o;
  }
}

// ---- GEMM1: h = lecun_tanh(X @ Wb^T + bb) ------------------------------
// M=16384 N=1024 K=768. 256 blocks; XCD map: br = (bid>>5)*8 + (bid&7).

__global__ __launch_bounds__(512, 2) void gemm1_kernel(
    const f16* __restrict__ X, const f16* __restrict__ Wb,
    const float* __restrict__ bb, f16* __restrict__ H) {
  constexpr int K = CAT_, BK = 64, NT = K / BK;  // 12
  __shared__ f16 As[2][2][8192];  // [dbuf][half][128*64]
  __shared__ f16 Bs[2][2][8192];
  const int t = threadIdx.x;
  const int lane = t & 63, wid = t >> 6;
  const int wr = wid >> 1;          // 0..3 (64-row band)
  const int wc = wid & 1;           // 0..1
  const int bc = (blockIdx.x >> 3) & 3;
  const int br = (blockIdx.x >> 5) * 8 + (blockIdx.x & 7);
  const int arow0 = br * 256;
  const int bn0 = bc * 256;

  f32x4 acc[4][8] = {};  // [m 0..3][set*4 + n]

  const int tr = t >> 3;                         // 0..63
  const int sch = ((t & 7) ^ (tr & 7)) * 8;      // pre-swizzled src chunk
  const f16* aSrc = X + (size_t)(arow0 + tr) * K + sch;
  const f16* bSrc = Wb + (size_t)(bn0 + tr) * K + sch;

  const int fr = lane & 15, klo = lane >> 4;
  const int cs0 = (klo ^ (fr & 7)) * 8;          // kk=0 phys chunk (f16 off)
  const int cs1 = ((klo + 4) ^ (fr & 7)) * 8;    // kk=1

#define SA(d, h, q, kt) gload_lds16(aSrc + (size_t)((h) * 128 + (q) * 64) * K + (kt) * BK, &As[d][h][(q) * 4096 + t * 8])
#define SB(d, h, q, kt) gload_lds16(bSrc + (size_t)((h) * 128 + (q) * 64) * K + (kt) * BK, &Bs[d][h][(q) * 4096 + t * 8])

  SA(0, 0, 0, 0); SA(0, 0, 1, 0); SA(0, 1, 0, 0); SA(0, 1, 1, 0);
  SB(0, 0, 0, 0); SB(0, 0, 1, 0); SB(0, 1, 0, 0); SB(0, 1, 1, 0);
  asm volatile("s_waitcnt vmcnt(0)" ::: "memory");
  BARRIER();

  const int ha = wr >> 1, ro = (wr & 1) * 64;

  for (int tt = 0; tt < NT; ++tt) {
    const int cur = tt & 1, nxt = cur ^ 1;
    const int ktn = tt + 1;
    const bool more = (ktn < NT);
    f16x8 a0[2][2], a1[2][2], b0[4][2], b1[4][2];

    // reads for cluster 1 only: a0 (4), b0 (8)
#pragma unroll
    for (int m = 0; m < 2; ++m) {
      const int r = (ro + m * 16 + fr) * 64;
      a0[m][0] = *((const f16x8*)(&As[cur][ha][r + cs0]));
      a0[m][1] = *((const f16x8*)(&As[cur][ha][r + cs1]));
    }
#pragma unroll
    for (int n = 0; n < 4; ++n) {
      const int r = (wc * 64 + n * 16 + fr) * 64;
      b0[n][0] = *((const f16x8*)(&Bs[cur][0][r + cs0]));
      b0[n][1] = *((const f16x8*)(&Bs[cur][0][r + cs1]));
    }
    // issue all next-tile stages early (latency hidden under this tile)
    if (more) {
      SA(nxt, 0, 0, ktn); SA(nxt, 0, 1, ktn); SA(nxt, 1, 0, ktn); SA(nxt, 1, 1, ktn);
      SB(nxt, 0, 0, ktn); SB(nxt, 0, 1, ktn); SB(nxt, 1, 0, ktn); SB(nxt, 1, 1, ktn);
    }
    // cluster 1: a0 x b0
    __builtin_amdgcn_s_setprio(1);
#pragma unroll
    for (int m = 0; m < 2; ++m)
#pragma unroll
      for (int n = 0; n < 4; ++n)
#pragma unroll
        for (int kk = 0; kk < 2; ++kk)
          acc[m][n] = MFMA16(a0[m][kk], b0[n][kk], acc[m][n]);
    __builtin_amdgcn_s_setprio(0);
    // b1 + a1 reads run under cluster-1's shadow
#pragma unroll
    for (int n = 0; n < 4; ++n) {
      const int r = (wc * 64 + n * 16 + fr) * 64;
      b1[n][0] = *((const f16x8*)(&Bs[cur][1][r + cs0]));
      b1[n][1] = *((const f16x8*)(&Bs[cur][1][r + cs1]));
    }
#pragma unroll
    for (int m = 0; m < 2; ++m) {
      const int r = (ro + 32 + m * 16 + fr) * 64;
      a1[m][0] = *((const f16x8*)(&As[cur][ha][r + cs0]));
      a1[m][1] = *((const f16x8*)(&As[cur][ha][r + cs1]));
    }
    // clusters 2-4
    __builtin_amdgcn_s_setprio(1);
#pragma unroll
    for (int m = 0; m < 2; ++m)
#pragma unroll
      for (int n = 0; n < 4; ++n)
#pragma unroll
        for (int kk = 0; kk < 2; ++kk)
          acc[m][4 + n] = MFMA16(a0[m][kk], b1[n][kk], acc[m][4 + n]);
#pragma unroll
    for (int m = 0; m < 2; ++m)
#pragma unroll
      for (int n = 0; n < 4; ++n)
#pragma unroll
        for (int kk = 0; kk < 2; ++kk)
          acc[2 + m][4 + n] = MFMA16(a1[m][kk], b1[n][kk], acc[2 + m][4 + n]);
#pragma unroll
    for (int m = 0; m < 2; ++m)
#pragma unroll
      for (int n = 0; n < 4; ++n)
#pragma unroll
        for (int kk = 0; kk < 2; ++kk)
          acc[2 + m][n] = MFMA16(a1[m][kk], b0[n][kk], acc[2 + m][n]);
    __builtin_amdgcn_s_setprio(0);
    if (more) {
      asm volatile("s_waitcnt vmcnt(0)" ::: "memory");
      BARRIER();
    }
  }
#undef SA
#undef SB

#pragma unroll
  for (int s = 0; s < 2; ++s) {
#pragma unroll
    for (int n = 0; n < 4; ++n) {
      const int colg = bn0 + s * 128 + wc * 64 + n * 16 + fr;
      const float bias = bb[colg];
#pragma unroll
      for (int m = 0; m < 4; ++m)
#pragma unroll
        for (int i = 0; i < 4; ++i) {
          const int rowg = arow0 + wr * 64 + m * 16 + klo * 4 + i;
          float v = acc[m][s * 4 + n][i] + bias;
          v = 1.7159f * fast_tanh(0.666f * v);
          H[(size_t)rowg * UNITS_ + colg] = (f16)v;
        }
    }
  }
}

// ---- GEMM2: four heads fused, same single-barrier template --------------
// M=16384 N'=2048(head-interleaved) K=1024. 512 blocks; XCD map:
// br = (bid>>6)*8 + (bid&7), bc = (bid>>3)&7.

__global__ __launch_bounds__(512, 2) void gemm2_kernel(
    const f16* __restrict__ Hm, const f16* __restrict__ Wp,
    const float* __restrict__ b1, const float* __restrict__ b2,
    const float* __restrict__ ba, const float* __restrict__ bt,
    const float* __restrict__ ts, float* __restrict__ out) {
  constexpr int K = UNITS_, BK = 64, NT = K / BK;  // 16
  __shared__ f16 As[2][2][8192];
  __shared__ f16 Bs[2][2][8192];
  const int t = threadIdx.x;
  const int lane = t & 63, wid = t >> 6;
  const int wr = wid >> 1;          // 0..3
  const int wc = wid & 1;           // 0..1
  const int bc = (blockIdx.x >> 3) & 7;
  const int br = (blockIdx.x >> 6) * 8 + (blockIdx.x & 7);
  const int arow0 = br * 256;
  const int bn0 = bc * 256;

  f32x4 acc[4][8] = {};  // [m][set*4 + head]

  const int tr = t >> 3;
  const int sch = ((t & 7) ^ (tr & 7)) * 8;
  const f16* aSrc = Hm + (size_t)(arow0 + tr) * K + sch;
  const f16* bSrc = Wp + (size_t)(bn0 + tr) * K + sch;

  const int fr = lane & 15, klo = lane >> 4;
  const int cs0 = (klo ^ (fr & 7)) * 8;
  const int cs1 = ((klo + 4) ^ (fr & 7)) * 8;

#define SA(d, h, q, kt) gload_lds16(aSrc + (size_t)((h) * 128 + (q) * 64) * K + (kt) * BK, &As[d][h][(q) * 4096 + t * 8])
#define SB(d, h, q, kt) gload_lds16(bSrc + (size_t)((h) * 128 + (q) * 64) * K + (kt) * BK, &Bs[d][h][(q) * 4096 + t * 8])

  SA(0, 0, 0, 0); SA(0, 0, 1, 0); SA(0, 1, 0, 0); SA(0, 1, 1, 0);
  SB(0, 0, 0, 0); SB(0, 0, 1, 0); SB(0, 1, 0, 0); SB(0, 1, 1, 0);
  asm volatile("s_waitcnt vmcnt(0)" ::: "memory");
  BARRIER();

  const int ha = wr >> 1, ro = (wr & 1) * 64;

  for (int tt = 0; tt < NT; ++tt) {
    const int cur = tt & 1, nxt = cur ^ 1;
    const int ktn = tt + 1;
    const bool more = (ktn < NT);
    f16x8 a0[2][2], a1[2][2], b0[4][2], b1[4][2];

    // reads for cluster 1 only: a0 (4), b0 (8)
#pragma unroll
    for (int m = 0; m < 2; ++m) {
      const int r = (ro + m * 16 + fr) * 64;
      a0[m][0] = *((const f16x8*)(&As[cur][ha][r + cs0]));
      a0[m][1] = *((const f16x8*)(&As[cur][ha][r + cs1]));
    }
#pragma unroll
    for (int n = 0; n < 4; ++n) {
      const int r = (wc * 64 + n * 16 + fr) * 64;
      b0[n][0] = *((const f16x8*)(&Bs[cur][0][r + cs0]));
      b0[n][1] = *((const f16x8*)(&Bs[cur][0][r + cs1]));
    }
    if (more) {
      SA(nxt, 0, 0, ktn); SA(nxt, 0, 1, ktn); SA(nxt, 1, 0, ktn); SA(nxt, 1, 1, ktn);
      SB(nxt, 0, 0, ktn); SB(nxt, 0, 1, ktn); SB(nxt, 1, 0, ktn); SB(nxt, 1, 1, ktn);
    }
    __builtin_amdgcn_s_setprio(1);
#pragma unroll
    for (int m = 0; m < 2; ++m)
#pragma unroll
      for (int n = 0; n < 4; ++n)
#pragma unroll
        for (int kk = 0; kk < 2; ++kk)
          acc[m][n] = MFMA16(a0[m][kk], b0[n][kk], acc[m][n]);
    __builtin_amdgcn_s_setprio(0);
#pragma unroll
    for (int n = 0; n < 4; ++n) {
      const int r = (wc * 64 + n * 16 + fr) * 64;
      b1[n][0] = *((const f16x8*)(&Bs[cur][1][r + cs0]));
      b1[n][1] = *((const f16x8*)(&Bs[cur][1][r + cs1]));
    }
#pragma unroll
    for (int m = 0; m < 2; ++m) {
      const int r = (ro + 32 + m * 16 + fr) * 64;
      a1[m][0] = *((const f16x8*)(&As[cur][ha][r + cs0]));
      a1[m][1] = *((const f16x8*)(&As[cur][ha][r + cs1]));
    }
    __builtin_amdgcn_s_setprio(1);
#pragma unroll
    for (int m = 0; m < 2; ++m)
#pragma unroll
      for (int n = 0; n < 4; ++n)
#pragma unroll
        for (int kk = 0; kk < 2; ++kk)
          acc[m][4 + n] = MFMA16(a0[m][kk], b1[n][kk], acc[m][4 + n]);
#pragma unroll
    for (int m = 0; m < 2; ++m)
#pragma unroll
      for (int n = 0; n < 4; ++n)
#pragma unroll
        for (int kk = 0; kk < 2; ++kk)
          acc[2 + m][4 + n] = MFMA16(a1[m][kk], b1[n][kk], acc[2 + m][4 + n]);
#pragma unroll
    for (int m = 0; m < 2; ++m)
#pragma unroll
      for (int n = 0; n < 4; ++n)
#pragma unroll
        for (int kk = 0; kk < 2; ++kk)
          acc[2 + m][n] = MFMA16(a1[m][kk], b0[n][kk], acc[2 + m][n]);
    __builtin_amdgcn_s_setprio(0);
    if (more) {
      asm volatile("s_waitcnt vmcnt(0)" ::: "memory");
      BARRIER();
    }
  }
#undef SA
#undef SB

  // epilogue: set s, frag n == head; hidcol = (bc*4 + s*2 + wc)*16 + fr
#pragma unroll
  for (int s = 0; s < 2; ++s) {
    const int colg = (bc * 4 + s * 2 + wc) * 16 + fr;  // 0..511
    const float B1 = b1[colg], B2 = b2[colg], BA = ba[colg], BT = bt[colg];
#pragma unroll
    for (int m = 0; m < 4; ++m)
#pragma unroll
      for (int i = 0; i < 4; ++i) {
        const int rowg = arow0 + wr * 64 + m * 16 + klo * 4 + i;
        const float ff1 = fast_tanh(acc[m][s * 4 + 0][i] + B1);
        const float ff2 = fast_tanh(acc[m][s * 4 + 1][i] + B2);
        const float ta = acc[m][s * 4 + 2][i] + BA;
        const float tb = acc[m][s * 4 + 3][i] + BT;
        const float z = ta * ts[rowg] + tb;
        const float ti = 1.0f / (1.0f + __expf(-z));
        out[(size_t)rowg * HID_ + colg] = ff1 + ti * (ff2 - ff1);
      }
  }
}

// ---- launch -------------------------------------------------------------

extern "C" void kernel_launch(void* const* d_in, const int* in_sizes, int n_in,
                              void* d_out, int out_size, void* d_ws, size_t ws_size,
                              hipStream_t stream) {
  const float* input = (const float*)d_in[0];
  const float* hx    = (const float*)d_in[1];
  const float* ts    = (const float*)d_in[2];
  const float* Wb    = (const float*)d_in[3];
  const float* bb    = (const float*)d_in[4];
  const float* W1    = (const float*)d_in[5];
  const float* b1    = (const float*)d_in[6];
  const float* W2    = (const float*)d_in[7];
  const float* b2    = (const float*)d_in[8];
  const float* Wa    = (const float*)d_in[9];
  const float* ba    = (const float*)d_in[10];
  const float* Wt    = (const float*)d_in[11];
  const float* bt    = (const float*)d_in[12];
  float* out = (float*)d_out;

  char* ws = (char*)d_ws;
  f16* x_f16  = (f16*)ws;  ws += (size_t)B_ * CAT_ * 2;
  f16* h_f16  = (f16*)ws;  ws += (size_t)B_ * UNITS_ * 2;
  f16* Wb_f16 = (f16*)ws;  ws += (size_t)UNITS_ * CAT_ * 2;
  f16* Wh_f16 = (f16*)ws;  ws += (size_t)4 * HID_ * UNITS_ * 2;

  prep_kernel<<<dim3(15104), 256, 0, stream>>>(input, hx, Wb, W1, W2, Wa, Wt,
                                               x_f16, Wb_f16, Wh_f16);
  gemm1_kernel<<<dim3(256), 512, 0, stream>>>(x_f16, Wb_f16, bb, h_f16);
  gemm2_kernel<<<dim3(512), 512, 0, stream>>>(h_f16, Wh_f16, b1, b2, ba, bt, ts, out);
}